// Round 8
// baseline (3716.641 us; speedup 1.0000x reference)
//
#include <hip/hip_runtime.h>
#include <cstdint>
#include <cstddef>

#define Hdim 512
#define Tdim 512
#define Bdim 32
#define NWG  256
#define SCAN_THREADS 384

typedef float        f32x4 __attribute__((ext_vector_type(4)));
typedef unsigned int u32x4 __attribute__((ext_vector_type(4)));
typedef unsigned int u32x2 __attribute__((ext_vector_type(2)));

__device__ __forceinline__ float sigmoidf_(float v) {
    return 1.f / (1.f + __expf(-v));
}
__device__ __forceinline__ float tanhf_(float a) {
    float ax = fabsf(a);
    float e  = __expf(-2.f * ax);
    float t  = (1.f - e) / (1.f + e);
    return copysignf(t, a);
}

// ---------------------------------------------------------------------------
// Tag-fused exchange GRU scan (round-5 chassis, dot phase remapped).
// WG = (bg = wg>>5: 4 batches) x (u = wg&31: 16 units x 3 gates = 48 W-rows).
// NEW dot mapping: thread (rw in [0,12), kq in [0,32)) owns 4 rows {rw+12i}
// x k-slices {4kq+128c, c=0..3}: each h b128 read feeds 16 FMAs (2x round 5),
// reads are consecutive quads across lanes (bank-uniform), LDS linear.
// Exchange (VERBATIM round 5): uint2 {h_bits, tag=t} per (batch,unit),
// sc0 sc1 via the L3 coherence point (sc0-only is SE scope — broken, r4/r6).
// Consumers poll dwordx4 until their 8 tags == t; h arrives fused with tags.
// Ping-pong: step t reads buf[t&1] (tag t), writes buf[(t+1)&1] (tag t+1).
// ---------------------------------------------------------------------------
__global__ void __launch_bounds__(SCAN_THREADS, 1)
gru_scan(const float* __restrict__ xp,    // [B][Tc][3H]
         const float* __restrict__ Whh,   // [3H][H]
         const float* __restrict__ bhh,   // [3H]
         const int*   __restrict__ lens,  // [B]
         float*       __restrict__ y,     // [B][T][H]
         u32x2*       hb2,                // [2][8][4][512] {h,tag}
         int t0, int Tc)
{
    __shared__ float  hlf[4 * Hdim];     // h, linear, 8 KB
    __shared__ float4 part4[8 * 49];     // dot partials [m][row(48,pad49)]

    const int tid = threadIdx.x;
    const int wg  = blockIdx.x;
    const int u   = wg & 31;
    const int bg  = wg >> 5;
    const int j0  = u << 4;
    const int b0  = bg << 2;
    const int rw  = tid >> 5;        // [0,12)
    const int kq  = tid & 31;        // [0,32)

    // ---- W_hh: 4 rows {rw+12i}, k floats {4kq + 128c .. +3}, registers ----
    float4 w[4][4];
#pragma unroll
    for (int i = 0; i < 4; ++i) {
        int r = rw + 12 * i;
        const float* p = Whh + ((size_t)(((r >> 4) << 9) + j0 + (r & 15)) << 9) + (kq << 2);
#pragma unroll
        for (int c = 0; c < 4; ++c) w[i][c] = *(const float4*)(p + (c << 7));
    }

    const bool isGate = tid < 64;
    const int gjl = tid & 15;
    const int gb  = (tid >> 4) & 3;
    const int jg  = j0 + gjl;
    int   glen = 0;
    float bh_r = 0.f, bh_z = 0.f, bh_n = 0.f;
    const float* xpb = nullptr;
    if (isGate) {
        glen = lens[b0 + gb];
        bh_r = bhh[jg];
        bh_z = bhh[512 + jg];
        bh_n = bhh[1024 + jg];
        xpb = xp + (size_t)(b0 + gb) * Tc * 1536;
    }

    // consumer poll constants (tid < 256): 8 {h,tag} pairs starting at tid*8
    // (entry = batch pb, units 8*(tid&63) .. +7 = quads pL, pL+1; linear LDS)
    const bool isPoll = tid < 256;
    const int  pb  = tid >> 6;
    const int  pL  = (tid & 63) << 1;
    float* lds_w0 = &hlf[(pb << 9) + (pL << 2)];
    float* lds_w1 = lds_w0 + 4;

    // xp values for step t0
    float xr = 0.f, xz = 0.f, xn = 0.f;
    if (isGate) {
        xr = xpb[jg];
        xz = xpb[512 + jg];
        xn = xpb[1024 + jg];
    }

    int budget = 1 << 20;   // safety: fail fast instead of hanging

    for (int t = t0; t < t0 + Tc; ++t) {
        const unsigned tg = (unsigned)t;

        // ---- poll buf[t&1] until all 8 tags == t; h arrives with tags ----
        if (isPoll) {
            const u32x2* src = hb2 + ((size_t)(t & 1) << 14) + (bg << 11) + (tid << 3);
            u32x4 q0, q1, q2, q3;
            for (;;) {
                asm volatile(
                    "global_load_dwordx4 %0, %4, off sc0 sc1\n\t"
                    "global_load_dwordx4 %1, %4, off offset:16 sc0 sc1\n\t"
                    "global_load_dwordx4 %2, %4, off offset:32 sc0 sc1\n\t"
                    "global_load_dwordx4 %3, %4, off offset:48 sc0 sc1\n\t"
                    "s_waitcnt vmcnt(0)"
                    : "=&v"(q0), "=&v"(q1), "=&v"(q2), "=&v"(q3)
                    : "v"(src) : "memory");
                bool ok = (q0[1] == tg) & (q0[3] == tg) & (q1[1] == tg) & (q1[3] == tg) &
                          (q2[1] == tg) & (q2[3] == tg) & (q3[1] == tg) & (q3[3] == tg);
                if (__all(ok)) break;
                if (--budget < 0) break;
            }
            f32x4 h0 = { __uint_as_float(q0[0]), __uint_as_float(q0[2]),
                         __uint_as_float(q1[0]), __uint_as_float(q1[2]) };
            f32x4 h1 = { __uint_as_float(q2[0]), __uint_as_float(q2[2]),
                         __uint_as_float(q3[0]), __uint_as_float(q3[2]) };
            *(f32x4*)lds_w0 = h0;
            *(f32x4*)lds_w1 = h1;
        }
        // next-step xp prefetch (issue now, consume next iteration)
        float xrn = 0.f, xzn = 0.f, xnn = 0.f;
        if (isGate) {
            int tf = (t + 1 < t0 + Tc) ? (t + 1 - t0) : (t - t0);
            const float* xq = xpb + (size_t)tf * 1536;
            xrn = xq[jg];
            xzn = xq[512 + jg];
            xnn = xq[1024 + jg];
        }
        __syncthreads();   // (b) h in LDS

        // ---- dots: 4 rows x 4 batches; h reads consecutive-quad, bank-clean ----
        float acc[4][4];
#pragma unroll
        for (int i = 0; i < 4; ++i)
#pragma unroll
            for (int b = 0; b < 4; ++b) acc[i][b] = 0.f;
#pragma unroll
        for (int b = 0; b < 4; ++b) {
            const float4* hb4 = (const float4*)&hlf[b << 9];
            float4 h0 = hb4[kq];
            float4 h1 = hb4[kq + 32];
            float4 h2 = hb4[kq + 64];
            float4 h3 = hb4[kq + 96];
#pragma unroll
            for (int i = 0; i < 4; ++i) {
                float a = acc[i][b];
                a = fmaf(w[i][0].x, h0.x, a); a = fmaf(w[i][0].y, h0.y, a);
                a = fmaf(w[i][0].z, h0.z, a); a = fmaf(w[i][0].w, h0.w, a);
                a = fmaf(w[i][1].x, h1.x, a); a = fmaf(w[i][1].y, h1.y, a);
                a = fmaf(w[i][1].z, h1.z, a); a = fmaf(w[i][1].w, h1.w, a);
                a = fmaf(w[i][2].x, h2.x, a); a = fmaf(w[i][2].y, h2.y, a);
                a = fmaf(w[i][2].z, h2.z, a); a = fmaf(w[i][2].w, h2.w, a);
                a = fmaf(w[i][3].x, h3.x, a); a = fmaf(w[i][3].y, h3.y, a);
                a = fmaf(w[i][3].z, h3.z, a); a = fmaf(w[i][3].w, h3.w, a);
                acc[i][b] = a;
            }
        }
        // 2-step butterfly over kq bits {0,1}; lanes kq%4==0 hold 64-k partials
#pragma unroll
        for (int mm = 1; mm <= 2; mm <<= 1)
#pragma unroll
            for (int i = 0; i < 4; ++i)
#pragma unroll
                for (int b = 0; b < 4; ++b)
                    acc[i][b] += __shfl_xor(acc[i][b], mm);
        if ((kq & 3) == 0) {
            int mp = kq >> 2;
#pragma unroll
            for (int i = 0; i < 4; ++i)
                part4[mp * 49 + rw + 12 * i] =
                    make_float4(acc[i][0], acc[i][1], acc[i][2], acc[i][3]);
        }
        __syncthreads();   // (c) partials ready

        // ---- gate wave: reduce 8 partials x 3 gates, gate math, fused store ----
        if (isGate) {
            const float* pf = (const float*)part4;
            float s0 = 0.f, s1 = 0.f, s2 = 0.f;
#pragma unroll
            for (int m = 0; m < 8; ++m) {
                int base = ((m * 49 + gjl) << 2) + gb;
                s0 += pf[base];
                s1 += pf[base + 64];    // +16 rows
                s2 += pf[base + 128];   // +32 rows
            }
            float hold = hlf[(gb << 9) + jg];
            float rr = sigmoidf_(xr + s0 + bh_r);
            float zz = sigmoidf_(xz + s1 + bh_z);
            float nn = tanhf_(xn + rr * (s2 + bh_n));
            float hnew = (1.f - zz) * nn + zz * hold;
            bool msk = t < glen;
            float hnext = msk ? hnew : hold;
            y[((size_t)(b0 + gb) * Tdim + t) * Hdim + jg] = msk ? hnew : 0.f;
            u32x2 pv;
            pv[0] = __float_as_uint(hnext);
            pv[1] = (unsigned)(t + 1);
            u32x2* dst = hb2 + ((size_t)((t + 1) & 1) << 14) + (bg << 11) + (gb << 9) + jg;
            asm volatile("global_store_dwordx2 %0, %1, off sc0 sc1"
                         :: "v"(dst), "v"(pv) : "memory");
            xr = xrn; xz = xzn; xn = xnn;
        }
        __syncthreads();   // (d) protect hlf/part4 from next iteration
    }
}

// ---------------------------------------------------------------------------
// fp32 NT-GEMM: C[m][n] = sum_k A[row(m)][k]*W[n][k] + bias[n]  (unchanged)
// ---------------------------------------------------------------------------
#define FMA4(c, a, b) { (c).x = fmaf((a), (b).x, (c).x); (c).y = fmaf((a), (b).y, (c).y); \
                        (c).z = fmaf((a), (b).z, (c).z); (c).w = fmaf((a), (b).w, (c).w); }

__global__ void __launch_bounds__(256)
gemm_xproj(const float* __restrict__ A,
           const float* __restrict__ W,     // [1536][512]
           const float* __restrict__ bias,  // [1536]
           float* __restrict__ C,           // [B*Tc][1536]
           int tcLog, int t0)
{
    __shared__ float As[16][132];
    __shared__ float Bs[16][132];
    const int tid = threadIdx.x;
    const int n0  = blockIdx.x << 7;
    const int m0  = blockIdx.y << 7;
    const int tx  = tid & 15;
    const int ty  = tid >> 4;

    const int mrow = tid >> 2;
    const int kcol = (tid & 3) << 2;
    const int Tcm1 = (1 << tcLog) - 1;

    int mg0 = m0 + mrow;
    int mg1 = m0 + 64 + mrow;
    size_t srow0 = (size_t)(mg0 >> tcLog) * Tdim + t0 + (mg0 & Tcm1);
    size_t srow1 = (size_t)(mg1 >> tcLog) * Tdim + t0 + (mg1 & Tcm1);
    const float* Ap0 = A + srow0 * Hdim + kcol;
    const float* Ap1 = A + srow1 * Hdim + kcol;
    const float* Wp0 = W + (size_t)(n0 + mrow) * Hdim + kcol;
    const float* Wp1 = W + (size_t)(n0 + 64 + mrow) * Hdim + kcol;

    float4 c00[4], c01[4], c10[4], c11[4];
#pragma unroll
    for (int i = 0; i < 4; ++i) {
        c00[i] = {0.f,0.f,0.f,0.f}; c01[i] = {0.f,0.f,0.f,0.f};
        c10[i] = {0.f,0.f,0.f,0.f}; c11[i] = {0.f,0.f,0.f,0.f};
    }

    float4 a0 = *(const float4*)(Ap0);
    float4 a1 = *(const float4*)(Ap1);
    float4 b0 = *(const float4*)(Wp0);
    float4 b1 = *(const float4*)(Wp1);

    for (int kt = 0; kt < 512; kt += 16) {
        __syncthreads();
        As[kcol+0][mrow] = a0.x; As[kcol+1][mrow] = a0.y;
        As[kcol+2][mrow] = a0.z; As[kcol+3][mrow] = a0.w;
        As[kcol+0][mrow+64] = a1.x; As[kcol+1][mrow+64] = a1.y;
        As[kcol+2][mrow+64] = a1.z; As[kcol+3][mrow+64] = a1.w;
        Bs[kcol+0][mrow] = b0.x; Bs[kcol+1][mrow] = b0.y;
        Bs[kcol+2][mrow] = b0.z; Bs[kcol+3][mrow] = b0.w;
        Bs[kcol+0][mrow+64] = b1.x; Bs[kcol+1][mrow+64] = b1.y;
        Bs[kcol+2][mrow+64] = b1.z; Bs[kcol+3][mrow+64] = b1.w;
        __syncthreads();
        if (kt + 16 < 512) {
            a0 = *(const float4*)(Ap0 + kt + 16);
            a1 = *(const float4*)(Ap1 + kt + 16);
            b0 = *(const float4*)(Wp0 + kt + 16);
            b1 = *(const float4*)(Wp1 + kt + 16);
        }
#pragma unroll
        for (int kk = 0; kk < 16; ++kk) {
            float4 aA = *(const float4*)&As[kk][ty * 4];
            float4 aB = *(const float4*)&As[kk][64 + ty * 4];
            float4 bA = *(const float4*)&Bs[kk][tx * 4];
            float4 bB = *(const float4*)&Bs[kk][64 + tx * 4];
            FMA4(c00[0], aA.x, bA); FMA4(c01[0], aA.x, bB);
            FMA4(c00[1], aA.y, bA); FMA4(c01[1], aA.y, bB);
            FMA4(c00[2], aA.z, bA); FMA4(c01[2], aA.z, bB);
            FMA4(c00[3], aA.w, bA); FMA4(c01[3], aA.w, bB);
            FMA4(c10[0], aB.x, bA); FMA4(c11[0], aB.x, bB);
            FMA4(c10[1], aB.y, bA); FMA4(c11[1], aB.y, bB);
            FMA4(c10[2], aB.z, bA); FMA4(c11[2], aB.z, bB);
            FMA4(c10[3], aB.w, bA); FMA4(c11[3], aB.w, bB);
        }
    }

    float4 biasA = *(const float4*)(bias + n0 + tx * 4);
    float4 biasB = *(const float4*)(bias + n0 + 64 + tx * 4);
#pragma unroll
    for (int i = 0; i < 4; ++i) {
        size_t row0 = (size_t)m0 + ty * 4 + i;
        size_t row1 = row0 + 64;
        float4 v;
        v.x = c00[i].x + biasA.x; v.y = c00[i].y + biasA.y;
        v.z = c00[i].z + biasA.z; v.w = c00[i].w + biasA.w;
        *(float4*)(C + row0 * 1536 + n0 + tx * 4) = v;
        v.x = c01[i].x + biasB.x; v.y = c01[i].y + biasB.y;
        v.z = c01[i].z + biasB.z; v.w = c01[i].w + biasB.w;
        *(float4*)(C + row0 * 1536 + n0 + 64 + tx * 4) = v;
        v.x = c10[i].x + biasA.x; v.y = c10[i].y + biasA.y;
        v.z = c10[i].z + biasA.z; v.w = c10[i].w + biasA.w;
        *(float4*)(C + row1 * 1536 + n0 + tx * 4) = v;
        v.x = c11[i].x + biasB.x; v.y = c11[i].y + biasB.y;
        v.z = c11[i].z + biasB.z; v.w = c11[i].w + biasB.w;
        *(float4*)(C + row1 * 1536 + n0 + 64 + tx * 4) = v;
    }
}

// ---------------------------------------------------------------------------
extern "C" void kernel_launch(void* const* d_in, const int* in_sizes, int n_in,
                              void* d_out, int out_size, void* d_ws, size_t ws_size,
                              hipStream_t stream) {
    (void)in_sizes; (void)n_in; (void)out_size;
    const float* x    = (const float*)d_in[0];
    const int*   lens = (const int*)d_in[1];
    const float* Wih0 = (const float*)d_in[2];
    const float* Whh0 = (const float*)d_in[3];
    const float* bih0 = (const float*)d_in[4];
    const float* bhh0 = (const float*)d_in[5];
    const float* Wih1 = (const float*)d_in[6];
    const float* Whh1 = (const float*)d_in[7];
    const float* bih1 = (const float*)d_in[8];
    const float* bhh1 = (const float*)d_in[9];
    float* out = (float*)d_out;

    // ws: [xp: B*Tc*1536 f32][hb2_0: 256KB][hb2_1: 256KB]
    const size_t hb2_bytes  = (size_t)2 * 8 * 2048 * 8;   // 2 bufs x 8 grp x 2048 pairs
    const size_t ctrl_bytes = 2 * hb2_bytes;
    int Tc = 512;
    while (Tc > 4 && (size_t)Bdim * Tc * 1536 * 4 + ctrl_bytes > ws_size) Tc >>= 1;
    int tcLog = 31 - __builtin_clz((unsigned)Tc);
    size_t xp_bytes = (size_t)Bdim * Tc * 1536 * 4;

    float* xp = (float*)d_ws;
    char*  ctrl = (char*)d_ws + xp_bytes;
    u32x2* hb2_0 = (u32x2*)ctrl;
    u32x2* hb2_1 = (u32x2*)(ctrl + hb2_bytes);

    (void)hipMemsetAsync(ctrl, 0, ctrl_bytes, stream);

    const int nChunks = Tdim / Tc;
    for (int layer = 0; layer < 2; ++layer) {
        const float* src  = layer ? (const float*)out : x;
        const float* Wih  = layer ? Wih1 : Wih0;
        const float* bih  = layer ? bih1 : bih0;
        const float* Whh  = layer ? Whh1 : Whh0;
        const float* bhhp = layer ? bhh1 : bhh0;
        u32x2* hb2 = layer ? hb2_1 : hb2_0;

        for (int c = 0; c < nChunks; ++c) {
            int t0 = c * Tc;
            dim3 gg(12, (Bdim * Tc) >> 7);
            gemm_xproj<<<gg, dim3(256), 0, stream>>>(src, Wih, bih, xp, tcLog, t0);

            const float* a_xp  = xp;
            const float* a_whh = Whh;
            const float* a_bhh = bhhp;
            const int*   a_ln  = lens;
            float*       a_y   = out;
            u32x2*       a_hb  = hb2;
            int a_t0 = t0;
            int a_tc = Tc;
            void* args[] = { &a_xp, &a_whh, &a_bhh, &a_ln, &a_y, &a_hb, &a_t0, &a_tc };
            (void)hipLaunchCooperativeKernel((const void*)gru_scan, dim3(NWG),
                                             dim3(SCAN_THREADS), args, 0, stream);
        }
    }
}